// Round 7
// baseline (42.218 us; speedup 1.0000x reference)
//
#include <hip/hip_runtime.h>
#include <hip/hip_fp16.h>

// C51 categorical projection — monotone register-walk, f16 LDS tile,
// NON-TEMPORAL probs LOADS + normal (allocating) output stores.
//
// Cache theory (from R6 evidence): with normal stores, the 107 MB output
// region occupies L3 (it's what evicted half of probs -> 54 MB refetch).
// So give L3 to the OUTPUT on purpose: nt loads keep probs from allocating,
// out stays L3-resident across graph replays (dirty lines overwritten in
// place, no HBM writeback while resident). Steady-state HBM traffic drops
// from ~160 MB mixed to ~110 MB read-only.

#define NUM_ATOMS 51
#define TPB 256

typedef float floatx4 __attribute__((ext_vector_type(4)));

constexpr int TILE_ELEMS = TPB * NUM_ATOMS;                // 13056 halves = 26112 B
constexpr int VEC_ITERS  = TILE_ELEMS / (4 * TPB);         // 12 float4 iters
constexpr int VEC_FLOATS = VEC_ITERS * 4 * TPB;            // 12288
constexpr int TAIL_ITERS = (TILE_ELEMS - VEC_FLOATS) / TPB; // 3 scalar iters

__global__ __launch_bounds__(TPB) void catproj_kernel(
    const float* __restrict__ reward,
    const float* __restrict__ probs,
    const float* __restrict__ not_done,
    float* __restrict__ out)
{
    __shared__ __align__(16) __half lds_h[TILE_ELEMS];
    const int t = threadIdx.x;
    const int blockBase = blockIdx.x * TILE_ELEMS;

    // ---- 1. coalesced staging: NT global f32 probs -> f16 LDS (flat) ----
    const floatx4* __restrict__ in4 = reinterpret_cast<const floatx4*>(probs + blockBase);
    #pragma unroll
    for (int i = 0; i < VEC_ITERS; ++i) {
        const int idx = i * TPB + t;
        const floatx4 v = __builtin_nontemporal_load(&in4[idx]);
        __half2 lo = __floats2half2_rn(v.x, v.y);
        __half2 hi = __floats2half2_rn(v.z, v.w);
        uint2 u;
        u.x = *reinterpret_cast<const unsigned int*>(&lo);
        u.y = *reinterpret_cast<const unsigned int*>(&hi);
        *reinterpret_cast<uint2*>(&lds_h[4 * idx]) = u;    // 8B aligned
    }
    #pragma unroll
    for (int i = 0; i < TAIL_ITERS; ++i) {
        const int f = VEC_FLOATS + i * TPB + t;
        lds_h[f] = __float2half(__builtin_nontemporal_load(&probs[blockBase + f]));
    }
    __syncthreads();

    // ---- 2. own row -> registers, then zero own row (own segment only,
    //         same-address dependence orders it -> NO barrier needed). ----
    const int row = t * NUM_ATOMS;
    float p[NUM_ATOMS];
    #pragma unroll
    for (int j = 0; j < NUM_ATOMS; ++j) p[j] = __half2float(lds_h[row + j]);
    #pragma unroll
    for (int j = 0; j < NUM_ATOMS; ++j) lds_h[row + j] = __half(0.0f);

    // ---- 3. monotone register walk, write-only f16 emission ----
    const int b = blockIdx.x * TPB + t;
    const float r = reward[b];
    const float g = 0.99f * not_done[b];          // exactly 0.0 or 0.99
    const float base = fmaf(2.5f, r, 25.0f);
    // fidx_j = clamp(base + g*(j-25), 0, 50) == (clip(r + g*z_j, -10,10)+10)*2.5

    float cur = 0.0f;   // mass for bin `prev`
    float nxt = 0.0f;   // mass for bin `prev + 1`
    int   prev = -1;

    #pragma unroll
    for (int j = 0; j < NUM_ATOMS; ++j) {
        float fidx = fmaf(g, (float)(j - 25), base);
        fidx = fminf(fmaxf(fidx, 0.0f), 50.0f);   // v_med3_f32
        const float lf = floorf(fidx);
        const int  li  = (int)lf;

        const bool adv = (li != prev);            // advance by exactly 1 (g<1)
        cur  = adv ? nxt  : cur;
        nxt  = adv ? 0.0f : nxt;
        prev = li;

        const float uc = fidx - lf;               // 0 when integral
        const float lc = 1.0f - uc;               // 1 when integral (matches ref)
        cur = fmaf(lc, p[j], cur);
        nxt = fmaf(uc, p[j], nxt);

        lds_h[row + li] = __float2half(cur);      // write-only; last write wins
    }
    {   // epilogue: flush upper neighbor (prev==50 -> fidx was exactly 50, nxt==0)
        const bool hasNext = (prev < NUM_ATOMS - 1);
        const int   ua = hasNext ? prev + 1 : prev;
        const float uv = hasNext ? nxt : cur;
        lds_h[row + ua] = __float2half(uv);
    }
    __syncthreads();

    // ---- 4. writeback: f16 LDS -> f32 global, NORMAL (allocating) stores ----
    floatx4* __restrict__ out4 = reinterpret_cast<floatx4*>(out + blockBase);
    #pragma unroll
    for (int i = 0; i < VEC_ITERS; ++i) {
        const int idx = i * TPB + t;
        const uint2 u = *reinterpret_cast<const uint2*>(&lds_h[4 * idx]);
        const __half2 lo = *reinterpret_cast<const __half2*>(&u.x);
        const __half2 hi = *reinterpret_cast<const __half2*>(&u.y);
        floatx4 v;
        v.x = __half2float(__low2half(lo));
        v.y = __half2float(__high2half(lo));
        v.z = __half2float(__low2half(hi));
        v.w = __half2float(__high2half(hi));
        out4[idx] = v;
    }
    #pragma unroll
    for (int i = 0; i < TAIL_ITERS; ++i) {
        const int f = VEC_FLOATS + i * TPB + t;
        out[blockBase + f] = __half2float(lds_h[f]);
    }
}

extern "C" void kernel_launch(void* const* d_in, const int* in_sizes, int n_in,
                              void* d_out, int out_size, void* d_ws, size_t ws_size,
                              hipStream_t stream) {
    const float* reward   = (const float*)d_in[0];
    const float* probs    = (const float*)d_in[1];
    const float* not_done = (const float*)d_in[2];
    float* out = (float*)d_out;

    const int bs = in_sizes[0];            // 524288
    const int blocks = bs / TPB;           // 2048

    hipLaunchKernelGGL(catproj_kernel, dim3(blocks), dim3(TPB), 0, stream,
                       reward, probs, not_done, out);
}

// Round 8
// 37.530 us; speedup vs baseline: 1.1249x; 1.1249x over previous
//
#include <hip/hip_runtime.h>
#include <hip/hip_fp16.h>

// C51 categorical projection — register-direct probs loads (f32 exact),
// monotone register walk, f16 bins tile in LDS, ONE barrier, nt writeback.
//
// Each thread's probs row is 51 contiguous f32 (204 B): load it straight
// into registers (12x dwordx4 + 3x dword, 4B-aligned). Removes the whole
// LDS input-staging phase (and its barrier + f16 input quantization).
// LDS holds only the 51-half bins row per thread (26112 B -> 6 blocks/CU).

#define NUM_ATOMS 51
#define TPB 256

typedef float floatx4 __attribute__((ext_vector_type(4)));

constexpr int TILE_ELEMS = TPB * NUM_ATOMS;                 // 13056 halves = 26112 B
constexpr int VEC_ITERS  = TILE_ELEMS / (4 * TPB);          // 12 float4 groups (writeback)
constexpr int VEC_FLOATS = VEC_ITERS * 4 * TPB;             // 12288
constexpr int TAIL_ITERS = (TILE_ELEMS - VEC_FLOATS) / TPB; // 3

__global__ __launch_bounds__(TPB) void catproj_kernel(
    const float* __restrict__ reward,
    const float* __restrict__ probs,
    const float* __restrict__ not_done,
    float* __restrict__ out)
{
    __shared__ __align__(16) __half lds_h[TILE_ELEMS];      // bins only
    const int t = threadIdx.x;
    const int b = blockIdx.x * TPB + t;
    const int blockBase = blockIdx.x * TILE_ELEMS;

    // ---- 1. own probs row -> registers, direct from global (exact f32) ----
    const float* __restrict__ rowp = probs + (size_t)b * NUM_ATOMS;
    float p[NUM_ATOMS];
    #pragma unroll
    for (int i = 0; i < 12; ++i) {
        const floatx4 v = *reinterpret_cast<const floatx4*>(rowp + 4 * i);
        p[4 * i + 0] = v.x;
        p[4 * i + 1] = v.y;
        p[4 * i + 2] = v.z;
        p[4 * i + 3] = v.w;
    }
    p[48] = rowp[48];
    p[49] = rowp[49];
    p[50] = rowp[50];

    // ---- 2. zero own bins row (own segment only -> no barrier needed) ----
    const int row = t * NUM_ATOMS;
    #pragma unroll
    for (int j = 0; j < NUM_ATOMS; ++j) lds_h[row + j] = __half(0.0f);

    // ---- 3. monotone register walk, write-only f16 emission ----
    const float r = reward[b];
    const float g = 0.99f * not_done[b];          // exactly 0.0 or 0.99
    const float base = fmaf(2.5f, r, 25.0f);
    // fidx_j = clamp(base + g*(j-25), 0, 50) == (clip(r + g*z_j, -10,10)+10)*2.5

    float cur = 0.0f;   // mass for bin `prev`
    float nxt = 0.0f;   // mass for bin `prev + 1`
    int   prev = -1;

    #pragma unroll
    for (int j = 0; j < NUM_ATOMS; ++j) {
        float fidx = fmaf(g, (float)(j - 25), base);
        fidx = fminf(fmaxf(fidx, 0.0f), 50.0f);   // v_med3_f32
        const float lf = floorf(fidx);
        const int  li  = (int)lf;

        const bool adv = (li != prev);            // advance by exactly 1 (g<1)
        cur  = adv ? nxt  : cur;
        nxt  = adv ? 0.0f : nxt;
        prev = li;

        const float uc = fidx - lf;               // 0 when integral
        const float lc = 1.0f - uc;               // 1 when integral (matches ref)
        cur = fmaf(lc, p[j], cur);
        nxt = fmaf(uc, p[j], nxt);

        lds_h[row + li] = __float2half(cur);      // write-only; last write wins
    }
    {   // epilogue: flush upper neighbor (prev==50 -> fidx was exactly 50, nxt==0)
        const bool hasNext = (prev < NUM_ATOMS - 1);
        const int   ua = hasNext ? prev + 1 : prev;
        const float uv = hasNext ? nxt : cur;
        lds_h[row + ua] = __float2half(uv);
    }
    __syncthreads();                              // the ONLY barrier

    // ---- 4. writeback: f16 LDS -> f32 global, non-temporal float4 stores ----
    floatx4* __restrict__ out4 = reinterpret_cast<floatx4*>(out + blockBase);
    #pragma unroll
    for (int i = 0; i < VEC_ITERS; ++i) {
        const int idx = i * TPB + t;
        const uint2 u = *reinterpret_cast<const uint2*>(&lds_h[4 * idx]);
        const __half2 lo = *reinterpret_cast<const __half2*>(&u.x);
        const __half2 hi = *reinterpret_cast<const __half2*>(&u.y);
        floatx4 v;
        v.x = __half2float(__low2half(lo));
        v.y = __half2float(__high2half(lo));
        v.z = __half2float(__low2half(hi));
        v.w = __half2float(__high2half(hi));
        __builtin_nontemporal_store(v, &out4[idx]);
    }
    #pragma unroll
    for (int i = 0; i < TAIL_ITERS; ++i) {
        const int f = VEC_FLOATS + i * TPB + t;
        __builtin_nontemporal_store(__half2float(lds_h[f]), &out[blockBase + f]);
    }
}

extern "C" void kernel_launch(void* const* d_in, const int* in_sizes, int n_in,
                              void* d_out, int out_size, void* d_ws, size_t ws_size,
                              hipStream_t stream) {
    const float* reward   = (const float*)d_in[0];
    const float* probs    = (const float*)d_in[1];
    const float* not_done = (const float*)d_in[2];
    float* out = (float*)d_out;

    const int bs = in_sizes[0];            // 524288
    const int blocks = bs / TPB;           // 2048

    hipLaunchKernelGGL(catproj_kernel, dim3(blocks), dim3(TPB), 0, stream,
                       reward, probs, not_done, out);
}